// Round 1
// baseline (296.531 us; speedup 1.0000x reference)
//
#include <hip/hip_runtime.h>
#include <math.h>

// out[h, i, j] = sum_k amp[k,h] * exp(-|wid[k,h]| * (off[k,h] - rel)^2),
//   rel = (S-1 + i - j) - S = i - j - 1
// Strategy: per block = (head h, 32-row strip). Needed score indices are the
// contiguous range [i0, i0 + S + TI - 2] -> compute into LDS, then stream the
// 32 x S strip to HBM with float4 stores. Pure write-bandwidth kernel.

#define TI 32          // rows per block
#define BLOCK 256

__global__ __launch_bounds__(BLOCK) void toeplitz_rbf_kernel(
    const float* __restrict__ koff, const float* __restrict__ kwid,
    const float* __restrict__ kamp, float* __restrict__ out,
    int S, int H, int K) {
  extern __shared__ float lds[];        // S + TI - 1 scores
  const int h  = blockIdx.y;
  const int i0 = blockIdx.x * TI;
  const int nscore = S + TI - 1;

  // Per-head coefficients (K expected == 5); broadcast loads, L2-resident.
  float o0=0,o1=0,o2=0,o3=0,o4=0, w0=0,w1=0,w2=0,w3=0,w4=0, a0=0,a1=0,a2=0,a3=0,a4=0;
  if (K > 0) { o0=koff[0*H+h]; w0=fabsf(kwid[0*H+h]); a0=kamp[0*H+h]; }
  if (K > 1) { o1=koff[1*H+h]; w1=fabsf(kwid[1*H+h]); a1=kamp[1*H+h]; }
  if (K > 2) { o2=koff[2*H+h]; w2=fabsf(kwid[2*H+h]); a2=kamp[2*H+h]; }
  if (K > 3) { o3=koff[3*H+h]; w3=fabsf(kwid[3*H+h]); a3=kamp[3*H+h]; }
  if (K > 4) { o4=koff[4*H+h]; w4=fabsf(kwid[4*H+h]); a4=kamp[4*H+h]; }

  // Phase 1: score table for this strip. Global score index g = i0 + t,
  // rel value = g - S.
  for (int t = threadIdx.x; t < nscore; t += BLOCK) {
    float rel = (float)(i0 + t - S);
    float d0 = o0 - rel, d1 = o1 - rel, d2 = o2 - rel, d3 = o3 - rel, d4 = o4 - rel;
    float s = a0 * __expf(-w0 * d0 * d0)
            + a1 * __expf(-w1 * d1 * d1)
            + a2 * __expf(-w2 * d2 * d2)
            + a3 * __expf(-w3 * d3 * d3)
            + a4 * __expf(-w4 * d4 * d4);
    lds[t] = s;
  }
  __syncthreads();

  // Phase 2: stream out. Row i, col j reads lds[(S-1) + (i-i0) - j].
  for (int di = 0; di < TI; ++di) {
    const int i = i0 + di;
    if (i >= S) break;
    float* __restrict__ orow = out + ((size_t)h * S + i) * (size_t)S;
    const int base = S - 1 + di;
    for (int j = threadIdx.x * 4; j < S; j += BLOCK * 4) {
      const int g = base - j;                 // min value of g-3 is 0
      float4 v = make_float4(lds[g], lds[g - 1], lds[g - 2], lds[g - 3]);
      *(float4*)(orow + j) = v;               // 16B coalesced store
    }
  }
}

extern "C" void kernel_launch(void* const* d_in, const int* in_sizes, int n_in,
                              void* d_out, int out_size, void* d_ws, size_t ws_size,
                              hipStream_t stream) {
  // d_in[0] = seq_len (scalar, device-resident; cannot sync-read under graph
  // capture). Derive S from out_size = H*S*S with K=5, H = in_sizes[1]/K.
  const float* koff = (const float*)d_in[1];
  const float* kwid = (const float*)d_in[2];
  const float* kamp = (const float*)d_in[3];
  float* out = (float*)d_out;

  const int K = 5;
  int H = (n_in > 1 && in_sizes[1] > 0) ? in_sizes[1] / K : 16;
  if (H <= 0) H = 16;
  long long ss = (long long)out_size / H;     // S*S
  int S = (int)(sqrt((double)ss) + 0.5);

  dim3 grid((S + TI - 1) / TI, H);
  size_t lds_bytes = (size_t)(S + TI - 1) * sizeof(float);
  toeplitz_rbf_kernel<<<grid, BLOCK, lds_bytes, stream>>>(koff, kwid, kamp, out, S, H, K);
}

// Round 2
// 259.450 us; speedup vs baseline: 1.1429x; 1.1429x over previous
//
#include <hip/hip_runtime.h>
#include <math.h>

// out[h, i, j] = scores[h, S-1 + i - j], scores = sum_k RBF_k(rel), rel = idx - S.
// Per block: (head h, TI-row strip). Phase 1 computes the contiguous score
// range [i0, i0+S+TI-2] into LDS. Phase 2 streams the strip out with float4
// stores; Toeplitz shift-by-one lets each thread keep a rolling 4-register
// window: 1 LDS read + 1 store per row instead of 4 reads (round-1 version
// had 8-way-conflicted descending scalar reads, 4 per store).

#define TI 32          // rows per block
#define BLOCK 256

__global__ __launch_bounds__(BLOCK) void toeplitz_rbf_kernel(
    const float* __restrict__ koff, const float* __restrict__ kwid,
    const float* __restrict__ kamp, float* __restrict__ out,
    int S, int H, int K) {
  extern __shared__ float lds[];        // S + TI - 1 scores (+1 pad slot)
  const int h  = blockIdx.y;
  const int i0 = blockIdx.x * TI;
  const int nscore = S + TI - 1;

  // Per-head coefficients (K == 5 expected); broadcast loads, L2-resident.
  float o0=0,o1=0,o2=0,o3=0,o4=0, w0=0,w1=0,w2=0,w3=0,w4=0, a0=0,a1=0,a2=0,a3=0,a4=0;
  if (K > 0) { o0=koff[0*H+h]; w0=fabsf(kwid[0*H+h]); a0=kamp[0*H+h]; }
  if (K > 1) { o1=koff[1*H+h]; w1=fabsf(kwid[1*H+h]); a1=kamp[1*H+h]; }
  if (K > 2) { o2=koff[2*H+h]; w2=fabsf(kwid[2*H+h]); a2=kamp[2*H+h]; }
  if (K > 3) { o3=koff[3*H+h]; w3=fabsf(kwid[3*H+h]); a3=kamp[3*H+h]; }
  if (K > 4) { o4=koff[4*H+h]; w4=fabsf(kwid[4*H+h]); a4=kamp[4*H+h]; }

  // Phase 1: lds[t] = score(i0 + t), rel = i0 + t - S.
  for (int t = threadIdx.x; t < nscore; t += BLOCK) {
    float rel = (float)(i0 + t - S);
    float d0 = o0 - rel, d1 = o1 - rel, d2 = o2 - rel, d3 = o3 - rel, d4 = o4 - rel;
    float s = a0 * __expf(-w0 * d0 * d0)
            + a1 * __expf(-w1 * d1 * d1)
            + a2 * __expf(-w2 * d2 * d2)
            + a3 * __expf(-w3 * d3 * d3)
            + a4 * __expf(-w4 * d4 * d4);
    lds[t] = s;
  }
  __syncthreads();

  // Phase 2: row i = i0+di, col j reads lds[S-1 + di - j]. Rolling window:
  // window for di+1 = window for di shifted in one new element.
  const int rows = (S - i0 < TI) ? (S - i0) : TI;
  for (int j = threadIdx.x * 4; j < S; j += BLOCK * 4) {
    const int t0 = S - 1 - j;           // window head for di = 0; t0-3 >= 0
    float e0 = lds[t0], e1 = lds[t0 - 1], e2 = lds[t0 - 2], e3 = lds[t0 - 3];
    float* __restrict__ p = out + ((size_t)h * S + i0) * (size_t)S + j;
    for (int di = 0; di < rows; ++di) {
      *(float4*)p = make_float4(e0, e1, e2, e3);
      p += S;
      // shift window: new head is lds[t0 + di + 1] (lds has +1 pad slot, so
      // the final-iteration speculative read stays in bounds)
      e3 = e2; e2 = e1; e1 = e0; e0 = lds[t0 + di + 1];
    }
  }
}

extern "C" void kernel_launch(void* const* d_in, const int* in_sizes, int n_in,
                              void* d_out, int out_size, void* d_ws, size_t ws_size,
                              hipStream_t stream) {
  // d_in[0] = seq_len (device scalar; can't sync-read under graph capture).
  // Derive S from out_size = H*S*S with K=5, H = in_sizes[1]/K.
  const float* koff = (const float*)d_in[1];
  const float* kwid = (const float*)d_in[2];
  const float* kamp = (const float*)d_in[3];
  float* out = (float*)d_out;

  const int K = 5;
  int H = (n_in > 1 && in_sizes[1] > 0) ? in_sizes[1] / K : 16;
  if (H <= 0) H = 16;
  long long ss = (long long)out_size / H;     // S*S
  int S = (int)(sqrt((double)ss) + 0.5);

  dim3 grid((S + TI - 1) / TI, H);
  size_t lds_bytes = (size_t)(S + TI) * sizeof(float);  // +1 pad slot
  toeplitz_rbf_kernel<<<grid, BLOCK, lds_bytes, stream>>>(koff, kwid, kamp, out, S, H, K);
}